// Round 1
// baseline (3104.139 us; speedup 1.0000x reference)
//
#include <hip/hip_runtime.h>

#define DF 96
#define BN_EPS 1e-3f

// GEMM: C[N,96] = prologue(A)[N,96] @ W[96,96]
// prologue (FUSE_BN): a = relu(a)*s[c] + t[c], s = g*rsqrt(v+eps), t = b - m*s
template<bool FUSE_BN>
__global__ __launch_bounds__(192) void gemm_bn_kernel(
    const float* __restrict__ A, const float* __restrict__ W,
    const float* __restrict__ g, const float* __restrict__ b,
    const float* __restrict__ m, const float* __restrict__ v,
    float* __restrict__ C, int N)
{
    __shared__ float sW[96 * 96];      // 36.9 KB
    __shared__ float sA[64 * 100];     // 25.6 KB (pad 96->100 breaks bank aliasing)
    __shared__ float sS[96], sT[96];

    const int tid  = threadIdx.x;
    const int row0 = blockIdx.x * 64;

    if (FUSE_BN && tid < 96) {
        float s = g[tid] * rsqrtf(v[tid] + BN_EPS);
        sS[tid] = s;
        sT[tid] = b[tid] - m[tid] * s;
    }
    // stage W: 2304 float4 / 192 threads = 12 each (coalesced)
    {
        const float4* Wv  = reinterpret_cast<const float4*>(W);
        float4*       sWv = reinterpret_cast<float4*>(sW);
        #pragma unroll
        for (int i = 0; i < 12; ++i) sWv[tid + 192 * i] = Wv[tid + 192 * i];
    }
    __syncthreads();   // sS/sT ready before A-staging uses them

    // stage A tile (64 rows) with fused ReLU+BN: 1536 float4 / 192 = 8 each
    #pragma unroll
    for (int i = 0; i < 8; ++i) {
        int f   = tid + 192 * i;          // float4 index within tile
        int row = f / 24;
        int cc  = (f % 24) * 4;
        int gr  = row0 + row;
        float4 val = make_float4(0.f, 0.f, 0.f, 0.f);
        if (gr < N) {
            val = *reinterpret_cast<const float4*>(A + (size_t)gr * DF + cc);
            if (FUSE_BN) {
                float* p = &val.x;
                #pragma unroll
                for (int j = 0; j < 4; ++j) {
                    float x_ = p[j];
                    x_ = x_ > 0.f ? x_ : 0.f;
                    p[j] = x_ * sS[cc + j] + sT[cc + j];
                }
            }
        }
        *reinterpret_cast<float4*>(sA + row * 100 + cc) = val;
    }
    __syncthreads();

    const int tx = tid % 24, ty = tid / 24;   // 24 col-groups x 8 row-groups
    const int c0 = tx * 4;
    float acc[8][4];
    #pragma unroll
    for (int i = 0; i < 8; ++i)
        for (int j = 0; j < 4; ++j) acc[i][j] = 0.f;

    for (int k = 0; k < 96; ++k) {
        float4 w4 = *reinterpret_cast<const float4*>(sW + k * 96 + c0);
        #pragma unroll
        for (int i = 0; i < 8; ++i) {
            float a = sA[(ty + 8 * i) * 100 + k];
            acc[i][0] += a * w4.x;
            acc[i][1] += a * w4.y;
            acc[i][2] += a * w4.z;
            acc[i][3] += a * w4.w;
        }
    }
    #pragma unroll
    for (int i = 0; i < 8; ++i) {
        int gr = row0 + ty + 8 * i;
        if (gr < N) {
            *reinterpret_cast<float4*>(C + (size_t)gr * DF + c0) =
                make_float4(acc[i][0], acc[i][1], acc[i][2], acc[i][3]);
        }
    }
}

// Edge scatter: agg[dst] += w * h[src], 24 threads (float4 each) per edge.
__global__ __launch_bounds__(256) void scatter_kernel(
    const float* __restrict__ h, const int* __restrict__ src,
    const int* __restrict__ dst, const float* __restrict__ ew,
    float* __restrict__ agg, int E)
{
    long long t = (long long)blockIdx.x * blockDim.x + threadIdx.x;
    if (t >= (long long)E * 24) return;
    int e  = (int)(t / 24);
    int cc = (int)(t % 24) * 4;
    int s  = src[e];
    int d  = dst[e];
    float w = ew[e];
    float4 hv = *reinterpret_cast<const float4*>(h + (size_t)s * DF + cc);
    float* out = agg + (size_t)d * DF + cc;
    atomicAdd(out + 0, w * hv.x);
    atomicAdd(out + 1, w * hv.y);
    atomicAdd(out + 2, w * hv.z);
    atomicAdd(out + 3, w * hv.w);
}

// Final: out = relu(agg)*s3 + t3 + x   (float4-vectorized)
__global__ __launch_bounds__(256) void final_kernel(
    const float* __restrict__ agg, const float* __restrict__ x,
    const float* __restrict__ g, const float* __restrict__ b,
    const float* __restrict__ m, const float* __restrict__ v,
    float* __restrict__ out, int total4)
{
    int i = blockIdx.x * blockDim.x + threadIdx.x;
    if (i >= total4) return;
    int cc = (i % 24) * 4;
    float4 a4 = reinterpret_cast<const float4*>(agg)[i];
    float4 x4 = reinterpret_cast<const float4*>(x)[i];
    float* pa = &a4.x;
    const float* px = &x4.x;
    float4 o;
    float* po = &o.x;
    #pragma unroll
    for (int j = 0; j < 4; ++j) {
        int c = cc + j;
        float s  = g[c] * rsqrtf(v[c] + BN_EPS);
        float t  = b[c] - m[c] * s;
        float a  = pa[j] > 0.f ? pa[j] : 0.f;
        po[j] = a * s + t + px[j];
    }
    reinterpret_cast<float4*>(out)[i] = o;
}

extern "C" void kernel_launch(void* const* d_in, const int* in_sizes, int n_in,
                              void* d_out, int out_size, void* d_ws, size_t ws_size,
                              hipStream_t stream)
{
    const float* x    = (const float*)d_in[0];
    const int*   esrc = (const int*)d_in[1];
    const int*   edst = (const int*)d_in[2];
    const float* ew   = (const float*)d_in[3];
    const float* w1   = (const float*)d_in[4];
    const float* w2   = (const float*)d_in[5];
    const float* w3   = (const float*)d_in[6];
    const float* g1 = (const float*)d_in[7],  *b1 = (const float*)d_in[8];
    const float* m1 = (const float*)d_in[9],  *v1 = (const float*)d_in[10];
    const float* g2 = (const float*)d_in[11], *b2 = (const float*)d_in[12];
    const float* m2 = (const float*)d_in[13], *v2 = (const float*)d_in[14];
    const float* g3 = (const float*)d_in[15], *b3 = (const float*)d_in[16];
    const float* m3 = (const float*)d_in[17], *v3 = (const float*)d_in[18];

    const int N = in_sizes[0] / DF;    // 50000
    const int E = in_sizes[1];         // 800000
    const size_t nbytes = (size_t)N * DF * sizeof(float);

    float* h   = (float*)d_out;        // reuse d_out as the h buffer
    float* agg = (float*)d_ws;         // 19.2 MB scratch

    const int gemm_grid    = (N + 63) / 64;
    const long long st     = (long long)E * 24;
    const int scatter_grid = (int)((st + 255) / 256);
    const int total4       = N * 24;
    const int final_grid   = (total4 + 255) / 256;

    // ---- layer 1 ----
    hipMemsetAsync(agg, 0, nbytes, stream);
    gemm_bn_kernel<false><<<gemm_grid, 192, 0, stream>>>(
        x, w1, nullptr, nullptr, nullptr, nullptr, h, N);
    scatter_kernel<<<scatter_grid, 256, 0, stream>>>(h, esrc, edst, ew, agg, E);

    // ---- layer 2 ----  (gemm reads agg before it is re-zeroed; stream-ordered)
    gemm_bn_kernel<true><<<gemm_grid, 192, 0, stream>>>(
        agg, w2, g1, b1, m1, v1, h, N);
    hipMemsetAsync(agg, 0, nbytes, stream);
    scatter_kernel<<<scatter_grid, 256, 0, stream>>>(h, esrc, edst, ew, agg, E);

    // ---- layer 3 ----
    gemm_bn_kernel<true><<<gemm_grid, 192, 0, stream>>>(
        agg, w3, g2, b2, m2, v2, h, N);
    hipMemsetAsync(agg, 0, nbytes, stream);
    scatter_kernel<<<scatter_grid, 256, 0, stream>>>(h, esrc, edst, ew, agg, E);

    // ---- final: BN3 + residual ----
    final_kernel<<<final_grid, 256, 0, stream>>>(
        agg, x, g3, b3, m3, v3, (float*)d_out, total4);
}

// Round 2
// 450.416 us; speedup vs baseline: 6.8917x; 6.8917x over previous
//
#include <hip/hip_runtime.h>

#define DF 96
#define BN_EPS 1e-3f
#define SCAN_B 1024   // elements per scan block (256 threads x 4)

// ---------------- GEMM: C[N,96] = prologue(A)[N,96] @ W[96,96] ----------------
// prologue (FUSE_BN): a = relu(a)*s[c] + t[c], s = g*rsqrt(v+eps), t = b - m*s
template<bool FUSE_BN>
__global__ __launch_bounds__(192) void gemm_bn_kernel(
    const float* __restrict__ A, const float* __restrict__ W,
    const float* __restrict__ g, const float* __restrict__ b,
    const float* __restrict__ m, const float* __restrict__ v,
    float* __restrict__ C, int N)
{
    __shared__ float sW[96 * 96];
    __shared__ float sA[64 * 100];
    __shared__ float sS[96], sT[96];

    const int tid  = threadIdx.x;
    const int row0 = blockIdx.x * 64;

    if (FUSE_BN && tid < 96) {
        float s = g[tid] * rsqrtf(v[tid] + BN_EPS);
        sS[tid] = s;
        sT[tid] = b[tid] - m[tid] * s;
    }
    {
        const float4* Wv  = reinterpret_cast<const float4*>(W);
        float4*       sWv = reinterpret_cast<float4*>(sW);
        #pragma unroll
        for (int i = 0; i < 12; ++i) sWv[tid + 192 * i] = Wv[tid + 192 * i];
    }
    __syncthreads();

    #pragma unroll
    for (int i = 0; i < 8; ++i) {
        int f   = tid + 192 * i;
        int row = f / 24;
        int cc  = (f % 24) * 4;
        int gr  = row0 + row;
        float4 val = make_float4(0.f, 0.f, 0.f, 0.f);
        if (gr < N) {
            val = *reinterpret_cast<const float4*>(A + (size_t)gr * DF + cc);
            if (FUSE_BN) {
                float* p = &val.x;
                #pragma unroll
                for (int j = 0; j < 4; ++j) {
                    float x_ = p[j];
                    x_ = x_ > 0.f ? x_ : 0.f;
                    p[j] = x_ * sS[cc + j] + sT[cc + j];
                }
            }
        }
        *reinterpret_cast<float4*>(sA + row * 100 + cc) = val;
    }
    __syncthreads();

    const int tx = tid % 24, ty = tid / 24;
    const int c0 = tx * 4;
    float acc[8][4];
    #pragma unroll
    for (int i = 0; i < 8; ++i)
        for (int j = 0; j < 4; ++j) acc[i][j] = 0.f;

    for (int k = 0; k < 96; ++k) {
        float4 w4 = *reinterpret_cast<const float4*>(sW + k * 96 + c0);
        #pragma unroll
        for (int i = 0; i < 8; ++i) {
            float a = sA[(ty + 8 * i) * 100 + k];
            acc[i][0] += a * w4.x;
            acc[i][1] += a * w4.y;
            acc[i][2] += a * w4.z;
            acc[i][3] += a * w4.w;
        }
    }
    #pragma unroll
    for (int i = 0; i < 8; ++i) {
        int gr = row0 + ty + 8 * i;
        if (gr < N) {
            *reinterpret_cast<float4*>(C + (size_t)gr * DF + c0) =
                make_float4(acc[i][0], acc[i][1], acc[i][2], acc[i][3]);
        }
    }
}

// ---------------- CSR build ----------------
__global__ __launch_bounds__(256) void hist_kernel(
    const int* __restrict__ dst, int* __restrict__ deg, int E)
{
    int i = blockIdx.x * blockDim.x + threadIdx.x;
    if (i < E) atomicAdd(&deg[dst[i]], 1);
}

// per-block (1024-elem) sums
__global__ __launch_bounds__(256) void scan_sum_kernel(
    const int* __restrict__ deg, int* __restrict__ bsum, int N)
{
    __shared__ int red[4];
    int base = blockIdx.x * SCAN_B;
    int t = threadIdx.x;
    int s = 0;
    #pragma unroll
    for (int j = 0; j < 4; ++j) {
        int idx = base + t + 256 * j;
        if (idx < N) s += deg[idx];
    }
    #pragma unroll
    for (int o = 32; o; o >>= 1) s += __shfl_down(s, o);
    if ((t & 63) == 0) red[t >> 6] = s;
    __syncthreads();
    if (t == 0) bsum[blockIdx.x] = red[0] + red[1] + red[2] + red[3];
}

// exclusive scan of block sums (small: ~49 entries), single block
__global__ void scan_bsum_kernel(int* __restrict__ bsum, int nb)
{
    if (threadIdx.x == 0) {
        int run = 0;
        for (int i = 0; i < nb; ++i) { int v = bsum[i]; bsum[i] = run; run += v; }
    }
}

// final exclusive scan -> row_ptr, cursor
__global__ __launch_bounds__(256) void scan_final_kernel(
    const int* __restrict__ deg, const int* __restrict__ bsum,
    int* __restrict__ row_ptr, int* __restrict__ cursor, int N, int E)
{
    __shared__ int wsum[4];
    int base = blockIdx.x * SCAN_B;
    int t = threadIdx.x;
    int lane = t & 63, wv = t >> 6;

    int vals[4];
    int s = 0;
    #pragma unroll
    for (int j = 0; j < 4; ++j) {
        int idx = base + t * 4 + j;
        vals[j] = (idx < N) ? deg[idx] : 0;
        s += vals[j];
    }
    int inc = s;
    #pragma unroll
    for (int o = 1; o < 64; o <<= 1) {
        int u = __shfl_up(inc, o);
        if (lane >= o) inc += u;
    }
    int excl = inc - s;
    if (lane == 63) wsum[wv] = inc;
    __syncthreads();
    if (t == 0) {
        int run = 0;
        #pragma unroll
        for (int j = 0; j < 4; ++j) { int v = wsum[j]; wsum[j] = run; run += v; }
    }
    __syncthreads();
    int off = bsum[blockIdx.x] + wsum[wv] + excl;
    #pragma unroll
    for (int j = 0; j < 4; ++j) {
        int idx = base + t * 4 + j;
        if (idx < N) { row_ptr[idx] = off; cursor[idx] = off; off += vals[j]; }
    }
    if (blockIdx.x == 0 && t == 0) row_ptr[N] = E;
}

__global__ __launch_bounds__(256) void fill_kernel(
    const int* __restrict__ src, const int* __restrict__ dst,
    const float* __restrict__ ew, int* __restrict__ cursor,
    int2* __restrict__ pairs, int E)
{
    int i = blockIdx.x * blockDim.x + threadIdx.x;
    if (i < E) {
        int p = atomicAdd(&cursor[dst[i]], 1);
        pairs[p] = make_int2(src[i], __float_as_int(ew[i]));
    }
}

// ---------------- Gather aggregation: agg[n][c] = sum_e w_e * h[src_e][c] ----
// 96 threads per node (thread = one feature column), 4 nodes per 384-thread block.
__global__ __launch_bounds__(384) void gather_kernel(
    const float* __restrict__ h, const int2* __restrict__ pairs,
    const int* __restrict__ row_ptr, float* __restrict__ agg, int N)
{
    int g = blockIdx.x * 4 + threadIdx.x / 96;
    int c = threadIdx.x % 96;
    if (g >= N) return;
    int e   = row_ptr[g];
    int end = row_ptr[g + 1];
    float acc = 0.f;
    for (; e + 1 < end; e += 2) {
        int2 p0 = pairs[e];
        int2 p1 = pairs[e + 1];
        float h0 = h[(size_t)p0.x * DF + c];
        float h1 = h[(size_t)p1.x * DF + c];
        acc += __int_as_float(p0.y) * h0;
        acc += __int_as_float(p1.y) * h1;
    }
    if (e < end) {
        int2 p0 = pairs[e];
        acc += __int_as_float(p0.y) * h[(size_t)p0.x * DF + c];
    }
    agg[(size_t)g * DF + c] = acc;
}

// ---------------- fallback atomic scatter (only if ws too small) -------------
__global__ __launch_bounds__(256) void scatter_kernel(
    const float* __restrict__ h, const int* __restrict__ src,
    const int* __restrict__ dst, const float* __restrict__ ew,
    float* __restrict__ agg, int E)
{
    long long t = (long long)blockIdx.x * blockDim.x + threadIdx.x;
    if (t >= (long long)E * 24) return;
    int e  = (int)(t / 24);
    int cc = (int)(t % 24) * 4;
    int s  = src[e];
    int d  = dst[e];
    float w = ew[e];
    float4 hv = *reinterpret_cast<const float4*>(h + (size_t)s * DF + cc);
    float* out = agg + (size_t)d * DF + cc;
    atomicAdd(out + 0, w * hv.x);
    atomicAdd(out + 1, w * hv.y);
    atomicAdd(out + 2, w * hv.z);
    atomicAdd(out + 3, w * hv.w);
}

// ---------------- Final: out = relu(agg)*s3 + t3 + x -------------------------
__global__ __launch_bounds__(256) void final_kernel(
    const float* __restrict__ agg, const float* __restrict__ x,
    const float* __restrict__ g, const float* __restrict__ b,
    const float* __restrict__ m, const float* __restrict__ v,
    float* __restrict__ out, int total4)
{
    int i = blockIdx.x * blockDim.x + threadIdx.x;
    if (i >= total4) return;
    int cc = (i % 24) * 4;
    float4 a4 = reinterpret_cast<const float4*>(agg)[i];
    float4 x4 = reinterpret_cast<const float4*>(x)[i];
    float* pa = &a4.x;
    const float* px = &x4.x;
    float4 o;
    float* po = &o.x;
    #pragma unroll
    for (int j = 0; j < 4; ++j) {
        int c = cc + j;
        float s  = g[c] * rsqrtf(v[c] + BN_EPS);
        float t  = b[c] - m[c] * s;
        float a  = pa[j] > 0.f ? pa[j] : 0.f;
        po[j] = a * s + t + px[j];
    }
    reinterpret_cast<float4*>(out)[i] = o;
}

extern "C" void kernel_launch(void* const* d_in, const int* in_sizes, int n_in,
                              void* d_out, int out_size, void* d_ws, size_t ws_size,
                              hipStream_t stream)
{
    const float* x    = (const float*)d_in[0];
    const int*   esrc = (const int*)d_in[1];
    const int*   edst = (const int*)d_in[2];
    const float* ew   = (const float*)d_in[3];
    const float* w1   = (const float*)d_in[4];
    const float* w2   = (const float*)d_in[5];
    const float* w3   = (const float*)d_in[6];
    const float* g1 = (const float*)d_in[7],  *b1 = (const float*)d_in[8];
    const float* m1 = (const float*)d_in[9],  *v1 = (const float*)d_in[10];
    const float* g2 = (const float*)d_in[11], *b2 = (const float*)d_in[12];
    const float* m2 = (const float*)d_in[13], *v2 = (const float*)d_in[14];
    const float* g3 = (const float*)d_in[15], *b3 = (const float*)d_in[16];
    const float* m3 = (const float*)d_in[17], *v3 = (const float*)d_in[18];

    const int N = in_sizes[0] / DF;    // 50000
    const int E = in_sizes[1];         // 800000
    const size_t nbytes = (size_t)N * DF * sizeof(float);

    float* h = (float*)d_out;          // d_out doubles as the h buffer

    // ---- workspace layout (all offsets 256B-aligned) ----
    auto up = [](size_t s) { return (s + 255) & ~(size_t)255; };
    size_t off_agg    = 0;
    size_t off_pairs  = off_agg   + up(nbytes);                 // E*8
    size_t off_deg    = off_pairs + up((size_t)E * 8);
    size_t off_rowptr = off_deg   + up((size_t)N * 4);
    size_t off_cursor = off_rowptr+ up(((size_t)N + 1) * 4);
    size_t off_bsum   = off_cursor+ up((size_t)N * 4);
    const int nb      = (N + SCAN_B - 1) / SCAN_B;
    size_t need       = off_bsum + up((size_t)nb * 4);

    char* ws = (char*)d_ws;
    float* agg = (float*)(ws + off_agg);

    const int gemm_grid  = (N + 63) / 64;
    const int total4     = N * 24;
    const int final_grid = (total4 + 255) / 256;

    if (ws_size >= need) {
        int2* pairs  = (int2*)(ws + off_pairs);
        int*  deg    = (int*) (ws + off_deg);
        int*  rowptr = (int*) (ws + off_rowptr);
        int*  cursor = (int*) (ws + off_cursor);
        int*  bsum   = (int*) (ws + off_bsum);

        // ---- build CSR (by dst) once ----
        hipMemsetAsync(deg, 0, (size_t)N * 4, stream);
        hist_kernel<<<(E + 255) / 256, 256, 0, stream>>>(edst, deg, E);
        scan_sum_kernel<<<nb, 256, 0, stream>>>(deg, bsum, N);
        scan_bsum_kernel<<<1, 64, 0, stream>>>(bsum, nb);
        scan_final_kernel<<<nb, 256, 0, stream>>>(deg, bsum, rowptr, cursor, N, E);
        fill_kernel<<<(E + 255) / 256, 256, 0, stream>>>(esrc, edst, ew, cursor, pairs, E);

        const int ggrid = (N + 3) / 4;   // 4 nodes per 384-thread block

        // ---- layer 1 ----
        gemm_bn_kernel<false><<<gemm_grid, 192, 0, stream>>>(
            x, w1, nullptr, nullptr, nullptr, nullptr, h, N);
        gather_kernel<<<ggrid, 384, 0, stream>>>(h, pairs, rowptr, agg, N);
        // ---- layer 2 ----
        gemm_bn_kernel<true><<<gemm_grid, 192, 0, stream>>>(
            agg, w2, g1, b1, m1, v1, h, N);
        gather_kernel<<<ggrid, 384, 0, stream>>>(h, pairs, rowptr, agg, N);
        // ---- layer 3 ----
        gemm_bn_kernel<true><<<gemm_grid, 192, 0, stream>>>(
            agg, w3, g2, b2, m2, v2, h, N);
        gather_kernel<<<ggrid, 384, 0, stream>>>(h, pairs, rowptr, agg, N);
    } else {
        // fallback: atomic scatter path (round-1 behavior)
        const long long st     = (long long)E * 24;
        const int scatter_grid = (int)((st + 255) / 256);

        hipMemsetAsync(agg, 0, nbytes, stream);
        gemm_bn_kernel<false><<<gemm_grid, 192, 0, stream>>>(
            x, w1, nullptr, nullptr, nullptr, nullptr, h, N);
        scatter_kernel<<<scatter_grid, 256, 0, stream>>>(h, esrc, edst, ew, agg, E);

        gemm_bn_kernel<true><<<gemm_grid, 192, 0, stream>>>(
            agg, w2, g1, b1, m1, v1, h, N);
        hipMemsetAsync(agg, 0, nbytes, stream);
        scatter_kernel<<<scatter_grid, 256, 0, stream>>>(h, esrc, edst, ew, agg, E);

        gemm_bn_kernel<true><<<gemm_grid, 192, 0, stream>>>(
            agg, w3, g2, b2, m2, v2, h, N);
        hipMemsetAsync(agg, 0, nbytes, stream);
        scatter_kernel<<<scatter_grid, 256, 0, stream>>>(h, esrc, edst, ew, agg, E);
    }

    // ---- final: BN3 + residual ----
    final_kernel<<<final_grid, 256, 0, stream>>>(
        agg, x, g3, b3, m3, v3, (float*)d_out, total4);
}

// Round 3
// 316.315 us; speedup vs baseline: 9.8135x; 1.4239x over previous
//
#include <hip/hip_runtime.h>

#define DF 96
#define BN_EPS 1e-3f
#define SCAN_B 1024   // elements per scan block (256 threads x 4)

// ---------------- GEMM: C[N,96] = prologue(A)[N,96] @ W[96,96] ----------------
// prologue (FUSE_BN): a = relu(a)*s[c] + t[c], s = g*rsqrt(v+eps), t = b - m*s
// In-place (C==A) is safe: each block reads only rows [row0,row0+64) into LDS
// (barrier) and writes only those same rows afterwards.
template<bool FUSE_BN>
__global__ __launch_bounds__(192) void gemm_bn_kernel(
    const float* __restrict__ A, const float* __restrict__ W,
    const float* __restrict__ g, const float* __restrict__ b,
    const float* __restrict__ m, const float* __restrict__ v,
    float* __restrict__ C, int N)
{
    __shared__ float sW[96 * 96];
    __shared__ float sA[64 * 100];
    __shared__ float sS[96], sT[96];

    const int tid  = threadIdx.x;
    const int row0 = blockIdx.x * 64;

    if (FUSE_BN && tid < 96) {
        float s = g[tid] * rsqrtf(v[tid] + BN_EPS);
        sS[tid] = s;
        sT[tid] = b[tid] - m[tid] * s;
    }
    {
        const float4* Wv  = reinterpret_cast<const float4*>(W);
        float4*       sWv = reinterpret_cast<float4*>(sW);
        #pragma unroll
        for (int i = 0; i < 12; ++i) sWv[tid + 192 * i] = Wv[tid + 192 * i];
    }
    __syncthreads();

    #pragma unroll
    for (int i = 0; i < 8; ++i) {
        int f   = tid + 192 * i;
        int row = f / 24;
        int cc  = (f % 24) * 4;
        int gr  = row0 + row;
        float4 val = make_float4(0.f, 0.f, 0.f, 0.f);
        if (gr < N) {
            val = *reinterpret_cast<const float4*>(A + (size_t)gr * DF + cc);
            if (FUSE_BN) {
                float* p = &val.x;
                #pragma unroll
                for (int j = 0; j < 4; ++j) {
                    float x_ = p[j];
                    x_ = x_ > 0.f ? x_ : 0.f;
                    p[j] = x_ * sS[cc + j] + sT[cc + j];
                }
            }
        }
        *reinterpret_cast<float4*>(sA + row * 100 + cc) = val;
    }
    __syncthreads();

    const int tx = tid % 24, ty = tid / 24;
    const int c0 = tx * 4;
    float acc[8][4];
    #pragma unroll
    for (int i = 0; i < 8; ++i)
        for (int j = 0; j < 4; ++j) acc[i][j] = 0.f;

    for (int k = 0; k < 96; ++k) {
        float4 w4 = *reinterpret_cast<const float4*>(sW + k * 96 + c0);
        #pragma unroll
        for (int i = 0; i < 8; ++i) {
            float a = sA[(ty + 8 * i) * 100 + k];
            acc[i][0] += a * w4.x;
            acc[i][1] += a * w4.y;
            acc[i][2] += a * w4.z;
            acc[i][3] += a * w4.w;
        }
    }
    #pragma unroll
    for (int i = 0; i < 8; ++i) {
        int gr = row0 + ty + 8 * i;
        if (gr < N) {
            *reinterpret_cast<float4*>(C + (size_t)gr * DF + c0) =
                make_float4(acc[i][0], acc[i][1], acc[i][2], acc[i][3]);
        }
    }
}

// ---------------- CSR build ----------------
__global__ __launch_bounds__(256) void hist_kernel(
    const int* __restrict__ dst, int* __restrict__ deg, int E)
{
    int i = blockIdx.x * blockDim.x + threadIdx.x;
    if (i < E) atomicAdd(&deg[dst[i]], 1);
}

__global__ __launch_bounds__(256) void scan_sum_kernel(
    const int* __restrict__ deg, int* __restrict__ bsum, int N)
{
    __shared__ int red[4];
    int base = blockIdx.x * SCAN_B;
    int t = threadIdx.x;
    int s = 0;
    #pragma unroll
    for (int j = 0; j < 4; ++j) {
        int idx = base + t + 256 * j;
        if (idx < N) s += deg[idx];
    }
    #pragma unroll
    for (int o = 32; o; o >>= 1) s += __shfl_down(s, o);
    if ((t & 63) == 0) red[t >> 6] = s;
    __syncthreads();
    if (t == 0) bsum[blockIdx.x] = red[0] + red[1] + red[2] + red[3];
}

__global__ void scan_bsum_kernel(int* __restrict__ bsum, int nb)
{
    if (threadIdx.x == 0) {
        int run = 0;
        for (int i = 0; i < nb; ++i) { int v = bsum[i]; bsum[i] = run; run += v; }
    }
}

__global__ __launch_bounds__(256) void scan_final_kernel(
    const int* __restrict__ deg, const int* __restrict__ bsum,
    int* __restrict__ row_ptr, int* __restrict__ cursor, int N, int E)
{
    __shared__ int wsum[4];
    int base = blockIdx.x * SCAN_B;
    int t = threadIdx.x;
    int lane = t & 63, wv = t >> 6;

    int vals[4];
    int s = 0;
    #pragma unroll
    for (int j = 0; j < 4; ++j) {
        int idx = base + t * 4 + j;
        vals[j] = (idx < N) ? deg[idx] : 0;
        s += vals[j];
    }
    int inc = s;
    #pragma unroll
    for (int o = 1; o < 64; o <<= 1) {
        int u = __shfl_up(inc, o);
        if (lane >= o) inc += u;
    }
    int excl = inc - s;
    if (lane == 63) wsum[wv] = inc;
    __syncthreads();
    if (t == 0) {
        int run = 0;
        #pragma unroll
        for (int j = 0; j < 4; ++j) { int v = wsum[j]; wsum[j] = run; run += v; }
    }
    __syncthreads();
    int off = bsum[blockIdx.x] + wsum[wv] + excl;
    #pragma unroll
    for (int j = 0; j < 4; ++j) {
        int idx = base + t * 4 + j;
        if (idx < N) { row_ptr[idx] = off; cursor[idx] = off; off += vals[j]; }
    }
    if (blockIdx.x == 0 && t == 0) row_ptr[N] = E;
}

__global__ __launch_bounds__(256) void fill_kernel(
    const int* __restrict__ src, const int* __restrict__ dst,
    const float* __restrict__ ew, int* __restrict__ cursor,
    int2* __restrict__ pairs, int E)
{
    int i = (blockIdx.x * blockDim.x + threadIdx.x) * 2;
    if (i >= E) return;
    int s0 = src[i]; int d0 = dst[i]; float w0 = ew[i];
    int p0 = atomicAdd(&cursor[d0], 1);
    pairs[p0] = make_int2(s0, __float_as_int(w0));
    if (i + 1 < E) {
        int s1 = src[i + 1]; int d1 = dst[i + 1]; float w1 = ew[i + 1];
        int p1 = atomicAdd(&cursor[d1], 1);
        pairs[p1] = make_int2(s1, __float_as_int(w1));
    }
}

// ---------------- Gather aggregation ----------------
// agg[n][c] = sum_e w_e * h[src_e][c]; 24 threads/node (float4 per thread),
// 8 nodes per 192-thread block, 4-edge unroll for MLP.
// FINAL: out = relu(acc)*s3 + t3 + x   (BN3 + residual fused)
template<bool FINAL>
__global__ __launch_bounds__(192) void gather_kernel(
    const float* __restrict__ h, const int2* __restrict__ pairs,
    const int* __restrict__ row_ptr, float* __restrict__ out,
    const float* __restrict__ xres,
    const float* __restrict__ g, const float* __restrict__ b,
    const float* __restrict__ m, const float* __restrict__ v, int N)
{
    __shared__ __attribute__((aligned(16))) float sS[96];
    __shared__ __attribute__((aligned(16))) float sT[96];
    if (FINAL) {
        int t = threadIdx.x;
        if (t < 96) {
            float s = g[t] * rsqrtf(v[t] + BN_EPS);
            sS[t] = s;
            sT[t] = b[t] - m[t] * s;
        }
        __syncthreads();
    }
    int node = blockIdx.x * 8 + threadIdx.x / 24;
    int q    = threadIdx.x % 24;
    if (node >= N) return;

    int e   = row_ptr[node];
    int end = row_ptr[node + 1];
    float ax = 0.f, ay = 0.f, az = 0.f, aw = 0.f;

    for (; e + 4 <= end; e += 4) {
        int2 p0 = pairs[e + 0];
        int2 p1 = pairs[e + 1];
        int2 p2 = pairs[e + 2];
        int2 p3 = pairs[e + 3];
        float4 v0 = *(reinterpret_cast<const float4*>(h + (size_t)p0.x * DF) + q);
        float4 v1 = *(reinterpret_cast<const float4*>(h + (size_t)p1.x * DF) + q);
        float4 v2 = *(reinterpret_cast<const float4*>(h + (size_t)p2.x * DF) + q);
        float4 v3 = *(reinterpret_cast<const float4*>(h + (size_t)p3.x * DF) + q);
        float w0 = __int_as_float(p0.y), w1 = __int_as_float(p1.y);
        float w2 = __int_as_float(p2.y), w3 = __int_as_float(p3.y);
        ax = fmaf(w0, v0.x, ax); ay = fmaf(w0, v0.y, ay);
        az = fmaf(w0, v0.z, az); aw = fmaf(w0, v0.w, aw);
        ax = fmaf(w1, v1.x, ax); ay = fmaf(w1, v1.y, ay);
        az = fmaf(w1, v1.z, az); aw = fmaf(w1, v1.w, aw);
        ax = fmaf(w2, v2.x, ax); ay = fmaf(w2, v2.y, ay);
        az = fmaf(w2, v2.z, az); aw = fmaf(w2, v2.w, aw);
        ax = fmaf(w3, v3.x, ax); ay = fmaf(w3, v3.y, ay);
        az = fmaf(w3, v3.z, az); aw = fmaf(w3, v3.w, aw);
    }
    for (; e < end; ++e) {
        int2 p = pairs[e];
        float4 hv = *(reinterpret_cast<const float4*>(h + (size_t)p.x * DF) + q);
        float w = __int_as_float(p.y);
        ax = fmaf(w, hv.x, ax); ay = fmaf(w, hv.y, ay);
        az = fmaf(w, hv.z, az); aw = fmaf(w, hv.w, aw);
    }

    size_t o = (size_t)node * DF + q * 4;
    if (FINAL) {
        int c = q * 4;
        float4 xv = *reinterpret_cast<const float4*>(xres + o);
        float4 s4 = *reinterpret_cast<const float4*>(sS + c);
        float4 t4 = *reinterpret_cast<const float4*>(sT + c);
        float4 r;
        r.x = fmaf(fmaxf(ax, 0.f), s4.x, t4.x) + xv.x;
        r.y = fmaf(fmaxf(ay, 0.f), s4.y, t4.y) + xv.y;
        r.z = fmaf(fmaxf(az, 0.f), s4.z, t4.z) + xv.z;
        r.w = fmaf(fmaxf(aw, 0.f), s4.w, t4.w) + xv.w;
        *reinterpret_cast<float4*>(out + o) = r;
    } else {
        *reinterpret_cast<float4*>(out + o) = make_float4(ax, ay, az, aw);
    }
}

// ---------------- fallback atomic scatter (only if ws too small) -------------
__global__ __launch_bounds__(256) void scatter_kernel(
    const float* __restrict__ h, const int* __restrict__ src,
    const int* __restrict__ dst, const float* __restrict__ ew,
    float* __restrict__ agg, int E)
{
    long long t = (long long)blockIdx.x * blockDim.x + threadIdx.x;
    if (t >= (long long)E * 24) return;
    int e  = (int)(t / 24);
    int cc = (int)(t % 24) * 4;
    int s  = src[e];
    int d  = dst[e];
    float w = ew[e];
    float4 hv = *reinterpret_cast<const float4*>(h + (size_t)s * DF + cc);
    float* out = agg + (size_t)d * DF + cc;
    atomicAdd(out + 0, w * hv.x);
    atomicAdd(out + 1, w * hv.y);
    atomicAdd(out + 2, w * hv.z);
    atomicAdd(out + 3, w * hv.w);
}

__global__ __launch_bounds__(256) void final_kernel(
    const float* __restrict__ agg, const float* __restrict__ x,
    const float* __restrict__ g, const float* __restrict__ b,
    const float* __restrict__ m, const float* __restrict__ v,
    float* __restrict__ out, int total4)
{
    int i = blockIdx.x * blockDim.x + threadIdx.x;
    if (i >= total4) return;
    int cc = (i % 24) * 4;
    float4 a4 = reinterpret_cast<const float4*>(agg)[i];
    float4 x4 = reinterpret_cast<const float4*>(x)[i];
    float* pa = &a4.x;
    const float* px = &x4.x;
    float4 o;
    float* po = &o.x;
    #pragma unroll
    for (int j = 0; j < 4; ++j) {
        int c = cc + j;
        float s  = g[c] * rsqrtf(v[c] + BN_EPS);
        float t  = b[c] - m[c] * s;
        float a  = pa[j] > 0.f ? pa[j] : 0.f;
        po[j] = a * s + t + px[j];
    }
    reinterpret_cast<float4*>(out)[i] = o;
}

extern "C" void kernel_launch(void* const* d_in, const int* in_sizes, int n_in,
                              void* d_out, int out_size, void* d_ws, size_t ws_size,
                              hipStream_t stream)
{
    const float* x    = (const float*)d_in[0];
    const int*   esrc = (const int*)d_in[1];
    const int*   edst = (const int*)d_in[2];
    const float* ew   = (const float*)d_in[3];
    const float* w1   = (const float*)d_in[4];
    const float* w2   = (const float*)d_in[5];
    const float* w3   = (const float*)d_in[6];
    const float* g1 = (const float*)d_in[7],  *b1 = (const float*)d_in[8];
    const float* m1 = (const float*)d_in[9],  *v1 = (const float*)d_in[10];
    const float* g2 = (const float*)d_in[11], *b2 = (const float*)d_in[12];
    const float* m2 = (const float*)d_in[13], *v2 = (const float*)d_in[14];
    const float* g3 = (const float*)d_in[15], *b3 = (const float*)d_in[16];
    const float* m3 = (const float*)d_in[17], *v3 = (const float*)d_in[18];

    const int N = in_sizes[0] / DF;    // 50000
    const int E = in_sizes[1];         // 800000
    const size_t nbytes = (size_t)N * DF * sizeof(float);

    float* B = (float*)d_out;          // d_out doubles as a working buffer

    // ---- workspace layout (256B-aligned) ----
    auto up = [](size_t s) { return (s + 255) & ~(size_t)255; };
    size_t off_agg    = 0;
    size_t off_pairs  = off_agg   + up(nbytes);
    size_t off_deg    = off_pairs + up((size_t)E * 8);
    size_t off_rowptr = off_deg   + up((size_t)N * 4);
    size_t off_cursor = off_rowptr+ up(((size_t)N + 1) * 4);
    size_t off_bsum   = off_cursor+ up((size_t)N * 4);
    const int nb      = (N + SCAN_B - 1) / SCAN_B;
    size_t need       = off_bsum + up((size_t)nb * 4);

    char* ws = (char*)d_ws;
    float* A = (float*)(ws + off_agg);

    const int gemm_grid  = (N + 63) / 64;

    if (ws_size >= need) {
        int2* pairs  = (int2*)(ws + off_pairs);
        int*  deg    = (int*) (ws + off_deg);
        int*  rowptr = (int*) (ws + off_rowptr);
        int*  cursor = (int*) (ws + off_cursor);
        int*  bsum   = (int*) (ws + off_bsum);

        // ---- build CSR (by dst) once ----
        hipMemsetAsync(deg, 0, (size_t)N * 4, stream);
        hist_kernel<<<(E + 255) / 256, 256, 0, stream>>>(edst, deg, E);
        scan_sum_kernel<<<nb, 256, 0, stream>>>(deg, bsum, N);
        scan_bsum_kernel<<<1, 64, 0, stream>>>(bsum, nb);
        scan_final_kernel<<<nb, 256, 0, stream>>>(deg, bsum, rowptr, cursor, N, E);
        fill_kernel<<<(E / 2 + 256) / 256, 256, 0, stream>>>(esrc, edst, ew, cursor, pairs, E);

        const int ggrid = (N + 7) / 8;   // 8 nodes per 192-thread block

        // ---- layer 1:  GEMM x->B, gather B->A ----
        gemm_bn_kernel<false><<<gemm_grid, 192, 0, stream>>>(
            x, w1, nullptr, nullptr, nullptr, nullptr, B, N);
        gather_kernel<false><<<ggrid, 192, 0, stream>>>(
            B, pairs, rowptr, A, nullptr, nullptr, nullptr, nullptr, nullptr, N);
        // ---- layer 2:  GEMM A->B (BN1 prologue), gather B->A ----
        gemm_bn_kernel<true><<<gemm_grid, 192, 0, stream>>>(
            A, w2, g1, b1, m1, v1, B, N);
        gather_kernel<false><<<ggrid, 192, 0, stream>>>(
            B, pairs, rowptr, A, nullptr, nullptr, nullptr, nullptr, nullptr, N);
        // ---- layer 3:  GEMM A->A in-place (BN2 prologue),
        //                gather A->d_out with fused BN3+residual ----
        gemm_bn_kernel<true><<<gemm_grid, 192, 0, stream>>>(
            A, w3, g2, b2, m2, v2, A, N);
        gather_kernel<true><<<ggrid, 192, 0, stream>>>(
            A, pairs, rowptr, B, x, g3, b3, m3, v3, N);
    } else {
        // fallback: atomic scatter path
        const long long st     = (long long)E * 24;
        const int scatter_grid = (int)((st + 255) / 256);
        const int total4       = N * 24;
        const int final_grid   = (total4 + 255) / 256;

        hipMemsetAsync(A, 0, nbytes, stream);
        gemm_bn_kernel<false><<<gemm_grid, 192, 0, stream>>>(
            x, w1, nullptr, nullptr, nullptr, nullptr, B, N);
        scatter_kernel<<<scatter_grid, 256, 0, stream>>>(B, esrc, edst, ew, A, E);

        gemm_bn_kernel<true><<<gemm_grid, 192, 0, stream>>>(
            A, w2, g1, b1, m1, v1, B, N);
        hipMemsetAsync(A, 0, nbytes, stream);
        scatter_kernel<<<scatter_grid, 256, 0, stream>>>(B, esrc, edst, ew, A, E);

        gemm_bn_kernel<true><<<gemm_grid, 192, 0, stream>>>(
            A, w3, g2, b2, m2, v2, B, N);
        hipMemsetAsync(A, 0, nbytes, stream);
        scatter_kernel<<<scatter_grid, 256, 0, stream>>>(B, esrc, edst, ew, A, E);

        final_kernel<<<final_grid, 256, 0, stream>>>(
            A, x, g3, b3, m3, v3, (float*)d_out, total4);
    }
}